// Round 15
// baseline (202.688 us; speedup 1.0000x reference)
//
#include <hip/hip_runtime.h>
#include <hip/hip_fp16.h>

// NCN fused per (b,h,chalf): 256 blocks x 512 thr = 8 waves, WAVE-SPECIALIZED:
// waves 0-3 = scan chains (c = cbase+wv), waves 4-7 = gemm/memory (W-frags,
// prefetch, stage, MFMA, MX scatter). 2 waves/SIMD -> gemm work fills the
// serial tanh chain's latency stalls via TLP. Double-buffered YL/MX, ONE
// barrier per chunk. y handoff f16 in d_ws dense 2KB rows (module 3 writes
// f32 directly to d_out, nothing reads it). Fallback (small ws): y f16 in
// d_out first-halves + expand. MFMA mapping + numerics = R13-validated.

typedef _Float16 f16;
typedef _Float16 half8 __attribute__((ext_vector_type(8)));
typedef _Float16 half4v __attribute__((ext_vector_type(4)));
typedef float f32x4 __attribute__((ext_vector_type(4)));
typedef unsigned uint4v __attribute__((ext_vector_type(4)));

constexpr int B = 8, T = 4096, D = 1024, H = 16, DH = 64, NC = 8, NM = 4;
constexpr int CH = 256;               // t-rows per chunk
constexpr int NCHUNK = T / CH;        // 16
constexpr int YLSZ = 128 * 128;       // 16KB staged rows
constexpr int MXSZ = 64 * 256;        // 16KB mix [e][c'*64B + k*2B]
constexpr size_t YWS_BYTES = (size_t)B * T * 2048;   // 64 MiB

template <bool YWS>
__global__ __launch_bounds__(512, 1)
void ncn_main(const float* __restrict__ x, const float* __restrict__ xa,
              const float* __restrict__ w, float* __restrict__ out,
              unsigned char* __restrict__ ybuf) {
  constexpr int YROW = YWS ? 2048 : 4096;   // y f16 row stride in ybuf
  __shared__ __align__(16) unsigned char YL[2 * YLSZ];
  __shared__ __align__(16) unsigned char MX[2 * MXSZ];

  const int tid = threadIdx.x, lane = tid & 63, wv = tid >> 6;
  const bool scanw = (wv < 4);
  const int gwv = wv & 3;                   // gemm wave id 0..3
  const int gtid = tid & 255;               // staging id within gemm waves
  const int bx = blockIdx.x;                // (b:8)(h:16)(chalf:2)
  const int chalf = bx & 1, h = (bx >> 1) & 15, b = bx >> 5;
  const int cbase = chalf * 4;
  const int lr = lane & 15, lg = lane >> 4;
  const int c = cbase + wv, d = lane;       // scan-wave chain identity (wv<4)

  unsigned char* const rows = (unsigned char*)out + (size_t)b * T * 4096;
  const unsigned char* const xrows =
      (const unsigned char*)x + (size_t)b * T * 4096;
  unsigned char* const ybase = ybuf + (size_t)b * T * YROW;

  float cache = scanw ? xa[((size_t)b * NC + c) * D + h * DH + d] : 0.f;

  uint4v pf[8];
  half8 Wf[4][2];
  float mixf[32];

  // ---- gemm-wave helpers (256 threads: gtid) ----
  auto prefetch = [&](int m, int t1) {
    if (m == 0) {
#pragma unroll
      for (int i = 0; i < 8; ++i) {
        const int gid = i * 256 + gtid;
        const int c16 = gid & 15, lt = gid >> 4;
        const int t = t1 + ((lt >> 2) << 3) + cbase + (lt & 3);
        pf[i] = *(const uint4v*)(xrows + (size_t)t * 4096 + h * 256 + c16 * 16);
      }
    } else {
#pragma unroll
      for (int i = 0; i < 4; ++i) {
        const int gid = i * 256 + gtid;
        const int c16 = gid & 7, lt = gid >> 3;
        const int t = t1 + ((lt >> 2) << 3) + cbase + (lt & 3);
        pf[i] = *(const uint4v*)(ybase + (size_t)t * YROW + h * 128 + c16 * 16);
      }
    }
  };
  auto stage = [&](int m, int buf) {
    unsigned char* yb = YL + buf * YLSZ;
    if (m == 0) {
#pragma unroll
      for (int i = 0; i < 8; ++i) {
        const int gid = i * 256 + gtid;
        const int c16 = gid & 15, lt = gid >> 4;
        const f32x4 v = __builtin_bit_cast(f32x4, pf[i]);
        half4v hv;
#pragma unroll
        for (int e = 0; e < 4; ++e) hv[e] = (f16)v[e];
        *(half4v*)(yb + lt * 128 + ((c16 * 8) ^ ((lt & 7) << 4))) = hv;
      }
    } else {
#pragma unroll
      for (int i = 0; i < 4; ++i) {
        const int gid = i * 256 + gtid;
        const int c16 = gid & 7, lt = gid >> 3;
        *(uint4v*)(yb + lt * 128 + ((c16 * 16) ^ ((lt & 7) << 4))) = pf[i];
      }
    }
  };
  auto gemm_do = [&](int buf) {             // issue + scatter (gemm waves)
    const unsigned char* yb = YL + buf * YLSZ;
    unsigned char* mb = MX + buf * MXSZ;
#pragma unroll
    for (int q = 0; q < 2; ++q) {
      const int tt = gwv * 2 + q;
      const int r = tt * 16 + lr;
      half8 Xf[2];
#pragma unroll
      for (int kt = 0; kt < 2; ++kt)
        Xf[kt] = *(const half8*)(yb + r * 128 +
                                 ((kt * 64 + lg * 16) ^ ((r & 7) << 4)));
      f32x4 acc[4];
#pragma unroll
      for (int it = 0; it < 4; ++it) acc[it] = (f32x4){0.f, 0.f, 0.f, 0.f};
#pragma unroll
      for (int kt = 0; kt < 2; ++kt)
#pragma unroll
        for (int it = 0; it < 4; ++it)
          acc[it] = __builtin_amdgcn_mfma_f32_16x16x32_f16(
              Xf[kt], Wf[it][kt], acc[it], 0, 0, 0);
#pragma unroll
      for (int it = 0; it < 4; ++it) {
        const int e = it * 16 + lr;
#pragma unroll
        for (int j = 0; j < 4; ++j)
          *(f16*)(mb + e * 256 +
                  ((j * 64 + (tt * 4 + lg) * 2) ^ ((e & 7) << 4))) =
              (f16)acc[it][j];
      }
    }
  };
  // ---- scan-wave helpers ----
  auto scan_load = [&](int buf) {
    const unsigned char* mb = MX + buf * MXSZ;
    half8 mxr[4];
#pragma unroll
    for (int k16 = 0; k16 < 4; ++k16)
      mxr[k16] = *(const half8*)(mb + d * 256 +
                                 ((wv * 64 + k16 * 16) ^ ((d & 7) << 4)));
#pragma unroll
    for (int k = 0; k < 32; ++k) mixf[k] = (float)mxr[k >> 3][k & 7];
  };
  auto scan_run = [&](int m, int t0) {
    if (m < 3 || !YWS) {                    // y f16 -> ybuf (own head bytes)
      unsigned char* sp = ybase + (size_t)(t0 + c) * YROW + h * 128 + 2 * d;
#pragma unroll
      for (int k = 0; k < 32; ++k) {
        const float z = cache + mixf[k];    // tanh(0.5(cache+mix))
        const float E = __expf(z);
        cache = fmaf(-2.0f, __builtin_amdgcn_rcpf(E + 1.0f), 1.0f);
        *(__half*)sp = __float2half_rn(cache);
        sp += 8 * YROW;
      }
    } else {                                // module 3, ws path: f32 -> d_out
      unsigned char* sp = rows + (size_t)(t0 + c) * 4096 + h * 256 + 4 * d;
#pragma unroll
      for (int k = 0; k < 32; ++k) {
        const float z = cache + mixf[k];
        const float E = __expf(z);
        cache = fmaf(-2.0f, __builtin_amdgcn_rcpf(E + 1.0f), 1.0f);
        *(float*)sp = cache;
        sp += 8 * 4096;
      }
    }
  };

  for (int m = 0; m < NM; ++m) {
    // module boundary: all scan-wave y stores drained, then visible to all
    asm volatile("s_waitcnt vmcnt(0)" ::: "memory");
    __syncthreads();

    if (!scanw) {
      // W fragments (R8-validated): Wf[it][kt][j] = W[m,h,kt*32+lg*8+j,it*16+lr]
      const float* wh = w + ((size_t)m * H + h) * DH * DH;
#pragma unroll
      for (int it = 0; it < 4; ++it)
#pragma unroll
        for (int kt = 0; kt < 2; ++kt)
#pragma unroll
          for (int j = 0; j < 8; ++j)
            Wf[it][kt][j] =
                (f16)wh[(size_t)(kt * 32 + lg * 8 + j) * DH + it * 16 + lr];
      prefetch(m, 0);
      stage(m, 0);
      prefetch(m, CH);
    }
    __syncthreads();                        // YL[0] ready
    if (!scanw) {
      gemm_do(0);
      stage(m, 1);
      prefetch(m, 2 * CH);
    }
    __syncthreads();                        // MX[0], YL[1] ready

    // steady state: scan(ch) on waves 0-3 || gemm(ch+1)+stage(ch+2)+pf(ch+3)
    for (int ch = 0; ch < NCHUNK; ++ch) {
      const int cb = ch & 1;
      if (scanw) {
        scan_load(cb);
        scan_run(m, ch * CH);
      } else {
        if (ch + 1 < NCHUNK) gemm_do(cb ^ 1);
        if (ch + 2 < NCHUNK) stage(m, cb);
        if (ch + 3 < NCHUNK) prefetch(m, (ch + 3) * CH);
      }
      __syncthreads();
    }
  }

  if (scanw) {
    float* ya = out + (size_t)B * T * D;
    ya[((size_t)b * NC + c) * D + h * DH + d] = cache;
  }
}

// ---- expand (fallback path): y f16 (first 2KB of row) -> f32 rows ----
__global__ __launch_bounds__(256)
void expand(float* __restrict__ buf) {
  __shared__ __align__(16) f16 rs[4 * 1024];
  const int tid = threadIdx.x;
  unsigned char* const base = (unsigned char*)buf + (size_t)blockIdx.x * 4 * 4096;
#pragma unroll
  for (int p = 0; p < 2; ++p) {
    const int gid = p * 256 + tid;
    const int row = gid >> 7, c16 = gid & 127;
    *(uint4v*)((unsigned char*)rs + row * 2048 + c16 * 16) =
        *(const uint4v*)(base + (size_t)row * 4096 + c16 * 16);
  }
  __syncthreads();
#pragma unroll
  for (int p = 0; p < 4; ++p) {
    const int gid = p * 256 + tid;
    const int row = gid >> 8, c4 = gid & 255;
    const half4v hv = *(const half4v*)((unsigned char*)rs + row * 2048 + c4 * 8);
    f32x4 v;
#pragma unroll
    for (int e = 0; e < 4; ++e) v[e] = (float)hv[e];
    *(f32x4*)(base + (size_t)row * 4096 + c4 * 16) = v;
  }
}

extern "C" void kernel_launch(void* const* d_in, const int* in_sizes, int n_in,
                              void* d_out, int out_size, void* d_ws, size_t ws_size,
                              hipStream_t stream) {
  (void)in_sizes; (void)n_in; (void)out_size;
  const float* x  = (const float*)d_in[0];
  const float* xa = (const float*)d_in[1];
  const float* w  = (const float*)d_in[2];
  float* out = (float*)d_out;

  const bool usews = (d_ws != nullptr) && (ws_size >= YWS_BYTES);
  if (usews) {
    hipLaunchKernelGGL((ncn_main<true>), dim3(256), dim3(512), 0, stream,
                       x, xa, w, out, (unsigned char*)d_ws);
  } else {
    hipLaunchKernelGGL((ncn_main<false>), dim3(256), dim3(512), 0, stream,
                       x, xa, w, out, (unsigned char*)out);
    hipLaunchKernelGGL(expand, dim3(B * T / 4), dim3(256), 0, stream, out);
  }
}

// Round 16
// 136.215 us; speedup vs baseline: 1.4880x; 1.4880x over previous
//
#include <hip/hip_runtime.h>
#include <hip/hip_fp16.h>

// NCN, fully wave-local: 1024 independent waves = chains (b,h,c). ZERO
// barriers, zero cross-wave LDS. Per wave, per module, per 32-step chunk:
// prefetch own y rows (global, line-coalesced) -> wave-private LDS Yst ->
// 16 MFMAs (mix for own steps) -> wave-private MX (cross-lane e-redistrib)
// -> batch mix load -> serial 32-step tanh scan -> y stores. y handoff in
// d_ws IN PLACE across modules (same rows, consumed-before-overwritten,
// same-wave order via vmcnt(0) per module). Module 3 writes f32 directly
// to d_out (nothing reads it). Fallback small-ws: y f16 in d_out row
// first-halves + expand kernel (R11-proven). MFMA mapping = R8-validated;
// scan carries u = y*log2e so the chain is add->v_exp->add->rcp->fma.

typedef _Float16 f16;
typedef _Float16 half8 __attribute__((ext_vector_type(8)));
typedef _Float16 half4v __attribute__((ext_vector_type(4)));
typedef float f32x4 __attribute__((ext_vector_type(4)));
typedef unsigned uint4v __attribute__((ext_vector_type(4)));

constexpr int B = 8, T = 4096, D = 1024, H = 16, DH = 64, NC = 8, NM = 4;
constexpr int KS = 32;               // scan steps per chunk
constexpr int NCH = (T / NC) / KS;   // 16 chunks per module
constexpr size_t YWS_BYTES = (size_t)B * T * 2048;   // 64 MiB
constexpr float L2E = 1.44269504088896340736f;

__device__ __forceinline__ float exp2_fast(float v) {
  float r;
  asm("v_exp_f32 %0, %1" : "=v"(r) : "v"(v));
  return r;
}

template <bool WS>
__global__ __launch_bounds__(256, 1)
void ncn_wave(const float* __restrict__ x, const float* __restrict__ xa,
              const float* __restrict__ w, float* __restrict__ out,
              unsigned char* __restrict__ ybuf) {
  constexpr int YROW = WS ? 2048 : 4096;   // y f16 row stride
  __shared__ __align__(16) unsigned char YST[4][4096];   // per-wave 32x128B
  __shared__ __align__(16) unsigned char MXS[4][8192];   // per-wave [e][128B]

  const int tid = threadIdx.x, lane = tid & 63, wv = tid >> 6;
  const int g = blockIdx.x * 4 + wv;        // chain id (b,h,c)
  const int c = g & 7, h = (g >> 3) & 15, b = g >> 7;
  const int lr = lane & 15, lg = lane >> 4;

  unsigned char* const yst = YST[wv];
  unsigned char* const mxs = MXS[wv];
  const unsigned char* const xb = (const unsigned char*)x + (size_t)b * T * 4096;
  unsigned char* const ob = (unsigned char*)out + (size_t)b * T * 4096;
  unsigned char* const yb = ybuf + (size_t)b * T * YROW;

  float y = xa[((size_t)b * NC + c) * D + h * DH + lane];
  float u = y * L2E;                        // carried: arg * log2(e)

  uint4v pf[8];
  half8 Wf[4][2];

  auto prefetch = [&](int m, int ch) {      // own rows of chunk ch -> pf
    const int J0 = ch * KS;
    if (m == 0) {                           // x f32: 32 rows x 256B
#pragma unroll
      for (int i = 0; i < 8; ++i) {
        const int lt = i * 4 + (lane >> 4);
        const int t = (J0 + lt) * 8 + c;
        pf[i] = *(const uint4v*)(xb + (size_t)t * 4096 + h * 256 + (lane & 15) * 16);
      }
    } else {                                // y f16: 32 rows x 128B
#pragma unroll
      for (int i = 0; i < 4; ++i) {
        const int lt = i * 8 + (lane >> 3);
        const int t = (J0 + lt) * 8 + c;
        pf[i] = *(const uint4v*)(yb + (size_t)t * YROW + h * 128 + (lane & 7) * 16);
      }
    }
  };
  auto stage = [&](int m) {                 // pf -> yst (swizzled f16 rows)
    if (m == 0) {
#pragma unroll
      for (int i = 0; i < 8; ++i) {
        const int lt = i * 4 + (lane >> 4);
        const f32x4 v = __builtin_bit_cast(f32x4, pf[i]);
        const __half2 p0 = __floats2half2_rn(v.x, v.y);
        const __half2 p1 = __floats2half2_rn(v.z, v.w);
        uint2 pk;
        pk.x = __builtin_bit_cast(unsigned, p0);
        pk.y = __builtin_bit_cast(unsigned, p1);
        *(uint2*)(yst + lt * 128 + (((lane & 15) * 8) ^ ((lt & 7) << 4))) = pk;
      }
    } else {
#pragma unroll
      for (int i = 0; i < 4; ++i) {
        const int lt = i * 8 + (lane >> 3);
        *(uint4v*)(yst + lt * 128 + (((lane & 7) * 16) ^ ((lt & 7) << 4))) = pf[i];
      }
    }
  };

  for (int m = 0; m < NM; ++m) {
    // W fragments (R8-validated): Wf[it][kt][j] = W[m,h, kt*32+lg*8+j, it*16+lr]
    const float* wh = w + ((size_t)m * H + h) * DH * DH;
#pragma unroll
    for (int it = 0; it < 4; ++it)
#pragma unroll
      for (int kt = 0; kt < 2; ++kt)
#pragma unroll
        for (int j = 0; j < 8; ++j)
          Wf[it][kt][j] =
              (f16)wh[(size_t)(kt * 32 + lg * 8 + j) * DH + it * 16 + lr];

    // same-wave RAW through global: drain previous module's y stores
    asm volatile("s_waitcnt vmcnt(0)" ::: "memory");

    prefetch(m, 0);
    stage(m);
    prefetch(m, 1);

    for (int ch = 0; ch < NCH; ++ch) {
      // ---- gemm on yst (chunk ch): staged row lt == step k
      f32x4 acc[2][4];
#pragma unroll
      for (int tq = 0; tq < 2; ++tq) {
        half8 Xf[2];
#pragma unroll
        for (int kt = 0; kt < 2; ++kt) {
          const int lt = tq * 16 + lr;
          Xf[kt] = *(const half8*)(yst + lt * 128 +
                                   ((kt * 64 + lg * 16) ^ ((lt & 7) << 4)));
        }
#pragma unroll
        for (int it = 0; it < 4; ++it) acc[tq][it] = (f32x4){0.f, 0.f, 0.f, 0.f};
#pragma unroll
        for (int kt = 0; kt < 2; ++kt)
#pragma unroll
          for (int it = 0; it < 4; ++it)
            acc[tq][it] = __builtin_amdgcn_mfma_f32_16x16x32_f16(
                Xf[kt], Wf[it][kt], acc[tq][it], 0, 0, 0);
      }
      asm volatile("s_waitcnt lgkmcnt(0)" ::: "memory");   // Xf landed; yst free
      if (ch + 1 < NCH) stage(m);                          // yst <- chunk ch+1
      if (ch + 2 < NCH) prefetch(m, ch + 2);               // pf  <- chunk ch+2

      // ---- scatter mix -> MX: row e = it*16+lr, k = tq*16+lg*4+jj (8B packed)
#pragma unroll
      for (int tq = 0; tq < 2; ++tq)
#pragma unroll
        for (int it = 0; it < 4; ++it) {
          const int e = it * 16 + lr;
          const __half2 p0 = __floats2half2_rn(acc[tq][it].x, acc[tq][it].y);
          const __half2 p1 = __floats2half2_rn(acc[tq][it].z, acc[tq][it].w);
          uint2 pk;
          pk.x = __builtin_bit_cast(unsigned, p0);
          pk.y = __builtin_bit_cast(unsigned, p1);
          *(uint2*)(mxs + e * 128 + ((tq * 32 + lg * 8) ^ ((e & 7) << 4))) = pk;
        }
      asm volatile("s_waitcnt lgkmcnt(0)" ::: "memory");   // MX visible

      // ---- scan: batch mix load (lane = e = d), off-chain cvt, serial loop
      half8 mxr[4];
#pragma unroll
      for (int k16 = 0; k16 < 4; ++k16)
        mxr[k16] = *(const half8*)(mxs + lane * 128 +
                                   ((k16 * 16) ^ ((lane & 7) << 4)));
      float mix2[KS];
#pragma unroll
      for (int k = 0; k < KS; ++k) mix2[k] = (float)mxr[k >> 3][k & 7] * L2E;

      const int t0 = ch * KS * 8 + c;        // t of step k: t0 + 8k
      if (m < 3 || !WS) {                    // y f16 -> ybuf rows
        unsigned char* sp = yb + (size_t)t0 * YROW + h * 128 + 2 * lane;
#pragma unroll
        for (int k = 0; k < KS; ++k) {
          const float z = u + mix2[k];       // tanh(0.5(cache+mix)), base-2
          const float E = exp2_fast(z);
          const float r = __builtin_amdgcn_rcpf(E + 1.0f);
          y = fmaf(r, -2.0f, 1.0f);
          u = fmaf(r, -2.0f * L2E, L2E);
          *(__half*)sp = __float2half_rn(y);
          sp += (size_t)8 * YROW;
        }
      } else {                               // module 3 (ws path): f32 -> d_out
        unsigned char* sp = ob + (size_t)t0 * 4096 + h * 256 + 4 * lane;
#pragma unroll
        for (int k = 0; k < KS; ++k) {
          const float z = u + mix2[k];
          const float E = exp2_fast(z);
          const float r = __builtin_amdgcn_rcpf(E + 1.0f);
          y = fmaf(r, -2.0f, 1.0f);
          u = fmaf(r, -2.0f * L2E, L2E);
          *(float*)sp = y;
          sp += (size_t)8 * 4096;
        }
      }
    }
  }

  float* ya = out + (size_t)B * T * D;
  ya[((size_t)b * NC + c) * D + h * DH + lane] = y;
}

// ---- expand (fallback path): y f16 (first 2KB of row) -> f32 rows ----
__global__ __launch_bounds__(256)
void expand(float* __restrict__ buf) {
  __shared__ __align__(16) f16 rs[4 * 1024];
  const int tid = threadIdx.x;
  unsigned char* const base = (unsigned char*)buf + (size_t)blockIdx.x * 4 * 4096;
#pragma unroll
  for (int p = 0; p < 2; ++p) {
    const int gid = p * 256 + tid;
    const int row = gid >> 7, c16 = gid & 127;
    *(uint4v*)((unsigned char*)rs + row * 2048 + c16 * 16) =
        *(const uint4v*)(base + (size_t)row * 4096 + c16 * 16);
  }
  __syncthreads();
#pragma unroll
  for (int p = 0; p < 4; ++p) {
    const int gid = p * 256 + tid;
    const int row = gid >> 8, c4 = gid & 255;
    const half4v hv = *(const half4v*)((unsigned char*)rs + row * 2048 + c4 * 8);
    f32x4 v;
#pragma unroll
    for (int e = 0; e < 4; ++e) v[e] = (float)hv[e];
    *(f32x4*)(base + (size_t)row * 4096 + c4 * 16) = v;
  }
}

extern "C" void kernel_launch(void* const* d_in, const int* in_sizes, int n_in,
                              void* d_out, int out_size, void* d_ws, size_t ws_size,
                              hipStream_t stream) {
  (void)in_sizes; (void)n_in; (void)out_size;
  const float* x  = (const float*)d_in[0];
  const float* xa = (const float*)d_in[1];
  const float* w  = (const float*)d_in[2];
  float* out = (float*)d_out;

  const bool usews = (d_ws != nullptr) && (ws_size >= YWS_BYTES);
  if (usews) {
    hipLaunchKernelGGL((ncn_wave<true>), dim3(256), dim3(256), 0, stream,
                       x, xa, w, out, (unsigned char*)d_ws);
  } else {
    hipLaunchKernelGGL((ncn_wave<false>), dim3(256), dim3(256), 0, stream,
                       x, xa, w, out, (unsigned char*)out);
    hipLaunchKernelGGL(expand, dim3(B * T / 4), dim3(256), 0, stream, out);
  }
}